// Round 3
// baseline (309.393 us; speedup 1.0000x reference)
//
#include <hip/hip_runtime.h>
#include <math.h>

#define SSM_N 64
#define SSM_H 1024
#define SSM_L 2048
#define SSM_B 8
#define FFTN 2048
#define NT 256
#define NT2 512

// XOR swizzle on float2 index: touches bits 0-3 only, so PSWZ(a+256q)=PSWZ(a)+256q.
#define PSWZ(a) ((a) ^ (((a) >> 4) & 15))

typedef float f2 __attribute__((ext_vector_type(2)));
static __device__ __forceinline__ f2 mkf2(float a, float b){ f2 v; v.x = a; v.y = b; return v; }

static __device__ __forceinline__ f2 cmul(f2 a, f2 b){
  return mkf2(-a.y, a.y) * mkf2(b.y, b.x) + mkf2(a.x, a.x) * b;
}
static __device__ __forceinline__ f2 cconj(f2 a){ return mkf2(a.x, -a.y); }

template<bool INV> static __device__ __forceinline__ f2 mul_mi(f2 a){
  return INV ? mkf2(-a.y, a.x) : mkf2(a.y, -a.x);
}
template<bool INV> static __device__ __forceinline__ f2 mul_w81(f2 a){
  const float r = 0.70710678118654752440f;
  return INV ? (r * mkf2(a.x - a.y, a.y + a.x)) : (r * mkf2(a.x + a.y, a.y - a.x));
}
template<bool INV> static __device__ __forceinline__ f2 mul_w83(f2 a){
  const float r = 0.70710678118654752440f;
  return INV ? (r * mkf2(-(a.x + a.y), a.x - a.y)) : (r * mkf2(a.y - a.x, -(a.x + a.y)));
}

// exp(-i*pi*k/8) table (cos, -sin)
#define W8C0 1.f
#define W8S0 0.f
#define W8C1 0.92387953251f
#define W8S1 (-0.38268343236f)
#define W8C2 0.70710678119f
#define W8S2 (-0.70710678119f)
#define W8C3 0.38268343236f
#define W8S3 (-0.92387953251f)
#define W8C4 0.f
#define W8S4 (-1.f)
#define W8C5 (-0.38268343236f)
#define W8S5 (-0.92387953251f)
#define W8C6 (-0.70710678119f)
#define W8S6 (-0.70710678119f)
#define W8C7 (-0.92387953251f)
#define W8S7 (-0.38268343236f)

template<bool INV>
static __device__ __forceinline__ void bfly8(const f2* x, f2* y)
{
  f2 t0=x[0]+x[4], t4=x[0]-x[4];
  f2 t1=x[1]+x[5], t5=x[1]-x[5];
  f2 t2=x[2]+x[6], t6=x[2]-x[6];
  f2 t3=x[3]+x[7], t7=x[3]-x[7];
  f2 b0=t0+t2, b2=t0-t2, b1=t1+t3, b3=t1-t3;
  f2 mb3 = mul_mi<INV>(b3);
  y[0]=b0+b1; y[4]=b0-b1; y[2]=b2+mb3; y[6]=b2-mb3;
  f2 v1 = mul_w81<INV>(t5), v2 = mul_mi<INV>(t6), v3 = mul_w83<INV>(t7);
  f2 a0=t4+v2, a2=t4-v2, a1=v1+v3, a3=v1-v3;
  f2 ma3 = mul_mi<INV>(a3);
  y[1]=a0+a1; y[5]=a0-a1; y[3]=a2+ma3; y[7]=a2-ma3;
}

template<bool INV>
static __device__ __forceinline__ void calc_w8(const f2* __restrict__ tw, int j, f2* w)
{
  f2 w1 = tw[j];
  if (INV) w1.y = -w1.y;
  w[1]=w1; w[2]=cmul(w1,w1); w[3]=cmul(w[2],w1); w[4]=cmul(w[2],w[2]);
  w[5]=cmul(w[3],w[2]); w[6]=cmul(w[3],w[3]); w[7]=cmul(w[4],w[3]);
}

static __device__ __forceinline__ void twstore(f2* __restrict__ dst, const f2* y, const f2* w,
                                               int base, int S)
{
  dst[PSWZ(base)]     = y[0];
  dst[PSWZ(base+S)]   = cmul(y[1],w[1]);
  dst[PSWZ(base+2*S)] = cmul(y[2],w[2]);
  dst[PSWZ(base+3*S)] = cmul(y[3],w[3]);
  dst[PSWZ(base+4*S)] = cmul(y[4],w[4]);
  dst[PSWZ(base+5*S)] = cmul(y[5],w[5]);
  dst[PSWZ(base+6*S)] = cmul(y[6],w[6]);
  dst[PSWZ(base+7*S)] = cmul(y[7],w[7]);
}

template<bool INV>
static __device__ __forceinline__ void bfly8_store(f2* __restrict__ dst, const f2* __restrict__ tw,
                                                   f2* x, int j, int base, int S)
{
  f2 y[8]; bfly8<INV>(x, y);
  f2 w[8]; calc_w8<INV>(tw, j, w);
  twstore(dst, y, w, base, S);
}

template<bool INV, bool ZTOP>
static __device__ __forceinline__ void stage8_first(const f2* __restrict__ src, f2* __restrict__ dst,
                                                    const f2* __restrict__ tw, int t, int st)
{
  const f2* sp = src + st;
  f2 x[8];
  if (ZTOP) {
    #pragma unroll
    for (int q = 0; q < 4; ++q) { x[q] = sp[256*q]; x[q+4] = mkf2(0.f, 0.f); }
  } else {
    #pragma unroll
    for (int q = 0; q < 8; ++q) x[q] = sp[256*q];
  }
  bfly8_store<INV>(dst, tw, x, t, t*8, 1);
}

template<bool INV, int S>
static __device__ __forceinline__ void stage8_mid(const f2* __restrict__ src, f2* __restrict__ dst,
                                                  const f2* __restrict__ tw, int t, int st)
{
  const f2* sp = src + st;
  f2 x[8];
  #pragma unroll
  for (int q = 0; q < 8; ++q) x[q] = sp[256*q];
  int i = t & (S-1);
  int j = t - i;
  bfly8_store<INV>(dst, tw, x, j, i + j*8, S);
}

// In-place mid stage: read 8 -> barrier -> write 8 (Stockham bijection => safe).
template<bool INV, int S>
static __device__ __forceinline__ void stage8_mid_ip(f2* __restrict__ buf, const f2* __restrict__ tw,
                                                     int t, int st)
{
  f2 x[8];
  #pragma unroll
  for (int q = 0; q < 8; ++q) x[q] = buf[st + 256*q];
  __syncthreads();
  int i = t & (S-1);
  int j = t - i;
  bfly8_store<INV>(buf, tw, x, j, i + j*8, S);
  __syncthreads();
}

template<bool INV, bool HALFOUT>
static __device__ __forceinline__ void stage4f(const f2* __restrict__ src, f2* __restrict__ dst, int st)
{
  #pragma unroll
  for (int hh = 0; hh < 2; ++hh) {
    const f2* sp = src + st + 256*hh;
    f2* wp = dst + st + 256*hh;
    f2 x0=sp[0], x1=sp[512], x2=sp[1024], x3=sp[1536];
    f2 a0=x0+x2, a2=x0-x2, a1=x1+x3, a3=x1-x3;
    f2 m = mul_mi<INV>(a3);
    wp[0]   = a0+a1;
    wp[512] = a2+m;
    if (!HALFOUT) {
      wp[1024] = a0-a1;
      wp[1536] = a2-m;
    }
  }
}

// In-place full-output radix-4 final stage: read 8 -> barrier -> write 8.
template<bool INV>
static __device__ __forceinline__ void stage4f_ip(f2* __restrict__ buf, int st)
{
  f2 xr[2][4];
  #pragma unroll
  for (int hh = 0; hh < 2; ++hh) {
    const f2* sp = buf + st + 256*hh;
    xr[hh][0]=sp[0]; xr[hh][1]=sp[512]; xr[hh][2]=sp[1024]; xr[hh][3]=sp[1536];
  }
  __syncthreads();
  #pragma unroll
  for (int hh = 0; hh < 2; ++hh) {
    f2* wp = buf + st + 256*hh;
    f2 a0=xr[hh][0]+xr[hh][2], a2=xr[hh][0]-xr[hh][2];
    f2 a1=xr[hh][1]+xr[hh][3], a3=xr[hh][1]-xr[hh][3];
    f2 m = mul_mi<INV>(a3);
    wp[0]    = a0+a1;
    wp[512]  = a2+m;
    wp[1024] = a0-a1;
    wp[1536] = a2-m;
  }
  __syncthreads();
}

// stage4 to registers: out[q] = element t+256q  (q = hh + 2k)
template<bool INV>
static __device__ __forceinline__ void stage4f_reg(const f2* __restrict__ src, f2* out, int st)
{
  #pragma unroll
  for (int hh = 0; hh < 2; ++hh) {
    const f2* sp = src + st + 256*hh;
    f2 x0=sp[0], x1=sp[512], x2=sp[1024], x3=sp[1536];
    f2 a0=x0+x2, a2=x0-x2, a1=x1+x3, a3=x1-x3;
    f2 m = mul_mi<INV>(a3);
    out[hh]   = a0+a1;
    out[hh+2] = a2+m;
    out[hh+4] = a0-a1;
    out[hh+6] = a2-m;
  }
}

static __device__ __forceinline__ f2 init_tw(f2* tw, int t)
{
  float s, c;
  sincosf(-6.2831853071795864769f * (float)t / (float)FFTN, &s, &c);
  f2 v = mkf2(c, s);
  tw[t] = v;   // exponents used are 0..248
  return v;    // u = exp(-2*pi*i*t/2048)
}

// Launch 1: fat kernel — blocks [0,4096): (B,L,H)->(B,H,L) transpose; blocks [4096,4160): cden.
__global__ __launch_bounds__(256) void kprep(
    const float* __restrict__ r, float* __restrict__ rT,
    const float* __restrict__ B_re, const float* __restrict__ B_im,
    const float* __restrict__ P_re, const float* __restrict__ P_im,
    const float* __restrict__ Q_re, const float* __restrict__ Q_im,
    const float* __restrict__ diag_re, const float* __restrict__ diag_im,
    const float* __restrict__ step,
    f2* __restrict__ cdenT, f2* __restrict__ f2v, f2* __restrict__ facv)
{
  __shared__ float til[64][65];
  int bid = blockIdx.x;
  int t = threadIdx.x;
  if (bid < 4096) {
    int tx = t & 15, ty = t >> 4;
    int h0 = (bid & 15) * 64, l0 = ((bid >> 4) & 31) * 64, b = bid >> 9;
    const float4* s4 = (const float4*)(r + ((size_t)b*SSM_L + l0)*SSM_H + h0);
    #pragma unroll
    for (int i = 0; i < 4; ++i) {
      int lr = ty + 16*i;
      float4 v = s4[(size_t)lr*(SSM_H/4) + tx];
      til[lr][4*tx+0]=v.x; til[lr][4*tx+1]=v.y; til[lr][4*tx+2]=v.z; til[lr][4*tx+3]=v.w;
    }
    __syncthreads();
    float4* d4 = (float4*)(rT + ((size_t)b*SSM_H + h0)*SSM_L + l0);
    #pragma unroll
    for (int i = 0; i < 4; ++i) {
      int hr = ty + 16*i;
      float4 w;
      w.x = til[4*tx+0][hr]; w.y = til[4*tx+1][hr];
      w.z = til[4*tx+2][hr]; w.w = til[4*tx+3][hr];
      d4[(size_t)hr*(SSM_L/4) + tx] = w;
    }
  } else {
    int gid = (bid - 4096) * 256 + t;     // 16384 threads, 8 per l
    int l = gid >> 3, s = gid & 7;
    double stepc = (double)step[0]; if (stepc < 1e-6) stepc = 1e-6;
    double ang = -2.0 * 3.14159265358979323846 * (double)l / (double)SSM_L;
    double zr = cos(ang), zi = sin(ang);
    double dr = 1.0 + zr, di = zi;
    double nr = 1.0 - zr, ni = -zi;
    double den = dr*dr + di*di;
    double i2s = 2.0 / stepc;
    double gr = i2s * (nr*dr + ni*di) / den;
    double gi = i2s * (ni*dr - nr*di) / den;
    double k10r=0.0, k10i=0.0, k11r=0.0, k11i=0.0;
    #pragma unroll
    for (int q = 0; q < 8; ++q) {
      int n = s*8 + q;
      double ar = gr - (double)diag_re[n];
      double ai = gi - (double)diag_im[n];
      double d2 = ar*ar + ai*ai;
      double cr = ar/d2, ci = -ai/d2;
      cdenT[n*SSM_L + l] = mkf2((float)cr, (float)ci);
      double qr = (double)Q_re[n], qi = (double)Q_im[n];
      double br = (double)B_re[n], bi = (double)B_im[n];
      double pr = (double)P_re[n], pi = (double)P_im[n];
      double qbr = qr*br - qi*bi, qbi = qr*bi + qi*br;
      double qpr = qr*pr - qi*pi, qpi = qr*pi + qi*pr;
      k10r += qbr*cr - qbi*ci; k10i += qbr*ci + qbi*cr;
      k11r += qpr*cr - qpi*ci; k11i += qpr*ci + qpi*cr;
    }
    #pragma unroll
    for (int off = 1; off < 8; off <<= 1) {
      k10r += __shfl_xor(k10r, off);
      k10i += __shfl_xor(k10i, off);
      k11r += __shfl_xor(k11r, off);
      k11i += __shfl_xor(k11i, off);
    }
    if (s == 0) {
      f2v[l] = mkf2((float)(2.0*dr/den), (float)(-2.0*di/den));
      double er = 1.0 + k11r, ei = k11i;
      double ed = er*er + ei*ei;
      facv[l] = mkf2((float)((k10r*er + k10i*ei)/ed), (float)((k10i*er - k10r*ei)/ed));
    }
  }
}

// Launch 2: 512 threads/block (8 waves -> 16 waves/CU at 2 blocks/CU).
// Contraction: all 512 threads, 4 l-values each, both channels (shared cd loads).
// FFT phase: WAVE-SPLIT — threads 0-255 run channel 0's pipeline, 256-511 channel 1's.
// PQ coefficients: X[k] = P_k*C[k] + Q_k*conj(C[2048-k]),
//   P_k = (K_k(1-s) + conj(K_kk)(1+s))/4096,  Q_k = i*c*(K_k - conj(K_kk))/4096,
//   (s,c) = sincos(pi*k/2048), kk = 2048-k (K[2048] partners k=0).
__global__ __launch_bounds__(NT2, 4) void kkern(
    const float* __restrict__ C_re, const float* __restrict__ C_im,
    const float* __restrict__ B_re, const float* __restrict__ B_im,
    const float* __restrict__ P_re, const float* __restrict__ P_im,
    const f2* __restrict__ cdenT, const f2* __restrict__ f2v, const f2* __restrict__ facv,
    float4* __restrict__ PQg)
{
  __shared__ f2 bufA[2][FFTN];
  __shared__ f2 bufB[2][FFTN];
  __shared__ f2 tw[256];
  int t = threadIdx.x;
  int tt = t & 255, ch = t >> 8, stt = PSWZ(tt);
  int h0 = blockIdx.x * 2;
  if (t < 256) init_tw(tw, t);
  f2* cbs = bufA[0];   // alias: dead once at_roots writes begin
  if (t < 128) {
    int h = h0 + (t >> 6), n = t & 63;
    f2 cc = mkf2(C_re[h*SSM_N + n], C_im[h*SSM_N + n]);
    cbs[t]       = cmul(cc, mkf2(B_re[n], B_im[n]));
    cbs[128 + t] = cmul(cc, mkf2(P_re[n], P_im[n]));
  }
  __syncthreads();
  f2 k00[2][4], k01[2][4];
  #pragma unroll
  for (int h2 = 0; h2 < 2; ++h2)
    #pragma unroll
    for (int i = 0; i < 4; ++i) { k00[h2][i] = mkf2(0.f,0.f); k01[h2][i] = mkf2(0.f,0.f); }
  f2 cd[4];
  #pragma unroll
  for (int i = 0; i < 4; ++i) cd[i] = cdenT[t + i*NT2];
  for (int n = 0; n < SSM_N; ++n) {
    f2 cdn[4];
    #pragma unroll
    for (int i = 0; i < 4; ++i) cdn[i] = cdenT[((n+1)&63)*SSM_L + t + i*NT2];
    #pragma unroll
    for (int h2 = 0; h2 < 2; ++h2) {
      f2 cb = cbs[h2*64 + n], cp = cbs[128 + h2*64 + n];
      #pragma unroll
      for (int i = 0; i < 4; ++i) {
        k00[h2][i] = k00[h2][i] + cmul(cb, cd[i]);
        k01[h2][i] = k01[h2][i] + cmul(cp, cd[i]);
      }
    }
    #pragma unroll
    for (int i = 0; i < 4; ++i) cd[i] = cdn[i];
  }
  __syncthreads();                          // contraction's cbs readers done
  #pragma unroll
  for (int h2 = 0; h2 < 2; ++h2)
    #pragma unroll
    for (int i = 0; i < 4; ++i) {
      int l = t + i*NT2;
      f2 fv = f2v[l], fc = facv[l];
      bufA[h2][PSWZ(l)] = cmul(fv, k00[h2][i] - cmul(k01[h2][i], fc));
    }
  __syncthreads();
  // ---- channel-split FFT phase: this thread owns channel ch, index tt ----
  f2* A  = bufA[ch];
  f2* Bb = bufB[ch];
  f2 ebin[4], e2048 = mkf2(0.f, 0.f);
  #pragma unroll
  for (int i = 0; i < 4; ++i) {             // even bins of K-hat (Hermitian part) -> regs
    int m = tt + i*256;
    if (m == 0) {
      ebin[0] = mkf2(A[0].x, 0.f);
      e2048   = mkf2(A[PSWZ(FFTN/2)].x, 0.f);
    } else {
      ebin[i] = 0.5f * (A[PSWZ(m)] + cconj(A[PSWZ(FFTN - m)]));
    }
  }
  stage8_first<true, false>(A, Bb, tw, tt, stt);     // iFFT stage 1
  __syncthreads();
  stage8_mid<true, 8>(Bb, A, tw, tt, stt);
  __syncthreads();
  stage8_mid<true, 64>(A, Bb, tw, tt, stt);
  __syncthreads();
  {                                         // iFFT stage4 -> regs; twist; fwd stage1 -> A
    f2 kr[8];
    stage4f_reg<true>(Bb, kr, stt);
    float sbb, cbb;
    sincosf(-3.14159265358979f * (float)tt / (float)FFTN, &sbb, &cbb);
    f2 cbase = mkf2(cbb, sbb);              // exp(-i*pi*tt/2048)
    const float Wc8[8] = {W8C0,W8C1,W8C2,W8C3,W8C4,W8C5,W8C6,W8C7};
    const float Ws8[8] = {W8S0,W8S1,W8S2,W8S3,W8S4,W8S5,W8S6,W8S7};
    const float scale = 1.0f / (float)FFTN;
    #pragma unroll
    for (int q = 0; q < 8; ++q) {
      f2 tq = cmul(cbase, mkf2(Wc8[q], Ws8[q]));
      kr[q] = (kr[q].x * scale) * tq;
    }
    f2 w[8]; calc_w8<false>(tw, tt, w);
    f2 y[8]; bfly8<false>(kr, y); twstore(A, y, w, tt*8, 1);
  }
  __syncthreads();
  stage8_mid<false, 8>(A, Bb, tw, tt, stt);
  __syncthreads();
  stage8_mid<false, 64>(Bb, A, tw, tt, stt);
  __syncthreads();
  // fwd stage4 (half out) A -> B lower; stash even bins -> B upper (natural; slot 0 = K[2048])
  stage4f<false, true>(A, Bb, stt);
  #pragma unroll
  for (int i = 0; i < 4; ++i) {
    int m = tt + 256*i;
    f2 v = ebin[i];
    if (m == 0) v = e2048;
    Bb[1024 + m] = v;
  }
  __syncthreads();
  // PQ emission; trig via tw-products: even angle pi*m/1024 -> u*W8[2i];
  // odd angle pi*(2m+1)/2048 -> (c1*u)*W8[2i], c1 = exp(-i*pi/2048).
  f2 u = tw[tt];                            // exp(-i*pi*tt/1024)
  const float q4 = 1.0f / 4096.0f;          // 1/2 (Hermitian) * 1/2048 (iFFT scale)
  const f2 c1 = mkf2(0.99999882345170176f, -0.00153398018628477f);
  f2 base_odd = cmul(c1, u);
  const float Wc8[8] = {W8C0,W8C1,W8C2,W8C3,W8C4,W8C5,W8C6,W8C7};
  const float Ws8[8] = {W8S0,W8S1,W8S2,W8S3,W8S4,W8S5,W8S6,W8S7};
  float4* pqrow = PQg + (size_t)(h0 + ch) * FFTN;
  #pragma unroll
  for (int i = 0; i < 4; ++i) {
    int m = tt + 256*i;
    // even k = 2m: Ka = own ebin; Kb = K[2048-2m] from stash (slot 0 holds K[2048])
    f2 Ka = ebin[i];
    f2 Kb = Bb[1024 + ((1024 - m) & 1023)];
    f2 ee = cmul(u, mkf2(Wc8[2*i], Ws8[2*i]));
    float cv = ee.x, sv = -ee.y;
    float am = q4*(1.f - sv), ap = q4*(1.f + sv), cq = q4*cv;
    f2 P = mkf2(Ka.x*am + Kb.x*ap, Ka.y*am - Kb.y*ap);
    f2 dd = mkf2(Ka.x - Kb.x, Ka.y + Kb.y);               // Ka - conj(Kb)
    pqrow[2*m] = make_float4(P.x, P.y, -dd.y*cq, dd.x*cq);
    // odd k = 2m+1: from fwd-FFT half output (swizzled, lower half of B)
    f2 Ko = Bb[PSWZ(m)];
    f2 Kp = Bb[PSWZ(1023 - m)];
    f2 eo = cmul(base_odd, mkf2(Wc8[2*i], Ws8[2*i]));
    cv = eo.x; sv = -eo.y;
    am = q4*(1.f - sv); ap = q4*(1.f + sv); cq = q4*cv;
    f2 P2 = mkf2(Ko.x*am + Kp.x*ap, Ko.y*am - Kp.y*ap);
    f2 d2 = mkf2(Ko.x - Kp.x, Ko.y + Kp.y);
    pqrow[2*m+1] = make_float4(P2.x, P2.y, -d2.y*cq, d2.x*cq);
  }
}

// Launch 3: per (b,h) row in rT: rfft4096 (packed) -> X[k]=P*C[k]+Q*conj(C[kk]) -> irfft + D*r.
// SINGLE in-place LDS buffer (18 KB) -> 8 blocks/CU (32 waves). Each stage: read 8 to regs ->
// barrier -> write 8 (bijective). XCD-bijective block map keeps PQ-row sharers on one XCD.
__global__ __launch_bounds__(NT, 8) void kconv(float* __restrict__ rT,
                                               const float4* __restrict__ PQg,
                                               const float* __restrict__ Dp)
{
  __shared__ f2 buf[FFTN];
  __shared__ f2 tw[256];
  int t = threadIdx.x, st = PSWZ(t);
  int xc = blockIdx.x & 7, y = blockIdx.x >> 3;
  int h = xc * 128 + (y >> 3);
  int b = y & 7;
  float Dv = Dp[0];
  init_tw(tw, t);
  float* rrow = rT + ((size_t)b*SSM_H + h) * SSM_L;
  const f2* r2 = (const f2*)rrow;
  f2 rv[4];
  #pragma unroll
  for (int i = 0; i < 4; ++i) rv[i] = r2[t + i*NT];   // element t+256i (also D-term src)
  {                                                   // fwd stage 1 from regs, upper half zero
    f2 xx[8];
    #pragma unroll
    for (int q = 0; q < 4; ++q) { xx[q] = rv[q]; xx[q+4] = mkf2(0.f, 0.f); }
    bfly8_store<false>(buf, tw, xx, t, t*8, 1);       // buf cold: no prior readers
  }
  __syncthreads();
  stage8_mid_ip<false, 8>(buf, tw, t, st);
  stage8_mid_ip<false, 64>(buf, tw, t, st);
  const float4* pqrow = PQg + (size_t)h * FFTN;       // issue PQ loads; hidden under stage4
  float4 pq[8];
  #pragma unroll
  for (int i = 0; i < 8; ++i) pq[i] = pqrow[t + i*NT];
  stage4f_ip<false>(buf, st);                         // full spectrum in buf (swizzled natural)
  {                                                   // pointwise in regs -> inv stage 1
    f2 xx[8];
    #pragma unroll
    for (int i = 0; i < 8; ++i) {
      int k = t + i*NT;
      int kk = (FFTN - k) & (FFTN - 1);
      f2 Ck  = buf[st + i*NT];                        // PSWZ(t+256i) = st+256i
      f2 Ckk = buf[PSWZ(kk)];
      xx[i] = cmul(mkf2(pq[i].x, pq[i].y), Ck) + cmul(mkf2(pq[i].z, pq[i].w), cconj(Ckk));
    }
    __syncthreads();
    bfly8_store<true>(buf, tw, xx, t, t*8, 1);
  }
  __syncthreads();
  stage8_mid_ip<true, 8>(buf, tw, t, st);
  stage8_mid_ip<true, 64>(buf, tw, t, st);
  f2* o2 = (f2*)rrow;                                 // fused inv stage4 (half out) + writeback
  #pragma unroll
  for (int hh = 0; hh < 2; ++hh) {
    const f2* sp = buf + st + 256*hh;
    f2 x0=sp[0], x1=sp[512], x2=sp[1024], x3=sp[1536];
    f2 a0=x0+x2, a2=x0-x2, a1=x1+x3, a3=x1-x3;
    f2 mm = mul_mi<true>(a3);
    f2 y0 = a0+a1, y1 = a2+mm;                        // elements t+256hh, t+256hh+512 (1/N in PQ)
    f2 rA = rv[hh], rB = rv[hh+2];
    o2[t + 256*hh]       = mkf2(y0.x + Dv*rA.x, y0.y + Dv*rA.y);
    o2[t + 256*hh + 512] = mkf2(y1.x + Dv*rB.x, y1.y + Dv*rB.y);
  }
}

// Launch 4: (B,H,L) -> (B,L,H) transpose + exact GELU
__global__ __launch_bounds__(256) void ktback(const float* __restrict__ yT, float* __restrict__ out)
{
  __shared__ float til[64][65];
  int t = threadIdx.x, tx = t & 15, ty = t >> 4;
  int h0 = blockIdx.x * 64, l0 = blockIdx.y * 64, b = blockIdx.z;
  const float4* s4 = (const float4*)(yT + ((size_t)b*SSM_H + h0)*SSM_L + l0);
  #pragma unroll
  for (int i = 0; i < 4; ++i) {
    int hr = ty + 16*i;
    float4 v = s4[(size_t)hr*(SSM_L/4) + tx];
    til[hr][4*tx+0]=v.x; til[hr][4*tx+1]=v.y; til[hr][4*tx+2]=v.z; til[hr][4*tx+3]=v.w;
  }
  __syncthreads();
  float4* d4 = (float4*)(out + ((size_t)b*SSM_L + l0)*SSM_H + h0);
  #pragma unroll
  for (int i = 0; i < 4; ++i) {
    int lr = ty + 16*i;
    float4 w;
    float x0 = til[4*tx+0][lr], x1 = til[4*tx+1][lr];
    float x2 = til[4*tx+2][lr], x3 = til[4*tx+3][lr];
    w.x = 0.5f * x0 * (1.0f + erff(x0 * 0.70710678118654752f));
    w.y = 0.5f * x1 * (1.0f + erff(x1 * 0.70710678118654752f));
    w.z = 0.5f * x2 * (1.0f + erff(x2 * 0.70710678118654752f));
    w.w = 0.5f * x3 * (1.0f + erff(x3 * 0.70710678118654752f));
    d4[(size_t)lr*(SSM_H/4) + tx] = w;
  }
}

extern "C" void kernel_launch(void* const* d_in, const int* in_sizes, int n_in,
                              void* d_out, int out_size, void* d_ws, size_t ws_size,
                              hipStream_t stream)
{
  const float* r       = (const float*)d_in[0];
  const float* B_re    = (const float*)d_in[1];
  const float* B_im    = (const float*)d_in[2];
  const float* C_re    = (const float*)d_in[3];
  const float* C_im    = (const float*)d_in[4];
  const float* P_re    = (const float*)d_in[5];
  const float* P_im    = (const float*)d_in[6];
  const float* Q_re    = (const float*)d_in[7];
  const float* Q_im    = (const float*)d_in[8];
  const float* diag_re = (const float*)d_in[9];
  const float* diag_im = (const float*)d_in[10];
  const float* step    = (const float*)d_in[11];
  const float* Dp      = (const float*)d_in[12];
  float* out = (float*)d_out;

  char* p = (char*)d_ws;
  float* rT  = (float*)p;  p += (size_t)SSM_B*SSM_H*SSM_L*sizeof(float);   // 64 MiB
  f2* cdenT  = (f2*)p;     p += (size_t)SSM_N*SSM_L*sizeof(f2);            // 1 MiB
  f2* f2v    = (f2*)p;     p += (size_t)SSM_L*sizeof(f2);
  f2* facv   = (f2*)p;     p += (size_t)SSM_L*sizeof(f2);
  float4* PQ = (float4*)p; p += (size_t)SSM_H*FFTN*sizeof(float4);         // 32 MiB

  kprep<<<4096 + 64, 256, 0, stream>>>(r, rT, B_re, B_im, P_re, P_im, Q_re, Q_im,
                                       diag_re, diag_im, step, cdenT, f2v, facv);
  kkern<<<SSM_H/2, NT2, 0, stream>>>(C_re, C_im, B_re, B_im, P_re, P_im,
                                     cdenT, f2v, facv, PQ);
  kconv<<<SSM_B*SSM_H, NT, 0, stream>>>(rT, PQ, Dp);
  ktback<<<dim3(SSM_H/64, SSM_L/64, SSM_B), 256, 0, stream>>>(rT, out);
}

// Round 4
// 284.452 us; speedup vs baseline: 1.0877x; 1.0877x over previous
//
#include <hip/hip_runtime.h>
#include <math.h>

#define SSM_N 64
#define SSM_H 1024
#define SSM_L 2048
#define SSM_B 8
#define FFTN 2048
#define NT 256
#define NT2 512

// XOR swizzle on float2 index: touches bits 0-3 only, so PSWZ(a+256q)=PSWZ(a)+256q.
#define PSWZ(a) ((a) ^ (((a) >> 4) & 15))

typedef float f2 __attribute__((ext_vector_type(2)));
static __device__ __forceinline__ f2 mkf2(float a, float b){ f2 v; v.x = a; v.y = b; return v; }

static __device__ __forceinline__ f2 cmul(f2 a, f2 b){
  return mkf2(-a.y, a.y) * mkf2(b.y, b.x) + mkf2(a.x, a.x) * b;
}
static __device__ __forceinline__ f2 cconj(f2 a){ return mkf2(a.x, -a.y); }

template<bool INV> static __device__ __forceinline__ f2 mul_mi(f2 a){
  return INV ? mkf2(-a.y, a.x) : mkf2(a.y, -a.x);
}
template<bool INV> static __device__ __forceinline__ f2 mul_w81(f2 a){
  const float r = 0.70710678118654752440f;
  return INV ? (r * mkf2(a.x - a.y, a.y + a.x)) : (r * mkf2(a.x + a.y, a.y - a.x));
}
template<bool INV> static __device__ __forceinline__ f2 mul_w83(f2 a){
  const float r = 0.70710678118654752440f;
  return INV ? (r * mkf2(-(a.x + a.y), a.x - a.y)) : (r * mkf2(a.y - a.x, -(a.x + a.y)));
}

// exp(-i*pi*k/8) table (cos, -sin)
#define W8C0 1.f
#define W8S0 0.f
#define W8C1 0.92387953251f
#define W8S1 (-0.38268343236f)
#define W8C2 0.70710678119f
#define W8S2 (-0.70710678119f)
#define W8C3 0.38268343236f
#define W8S3 (-0.92387953251f)
#define W8C4 0.f
#define W8S4 (-1.f)
#define W8C5 (-0.38268343236f)
#define W8S5 (-0.92387953251f)
#define W8C6 (-0.70710678119f)
#define W8S6 (-0.70710678119f)
#define W8C7 (-0.92387953251f)
#define W8S7 (-0.38268343236f)

template<bool INV>
static __device__ __forceinline__ void bfly8(const f2* x, f2* y)
{
  f2 t0=x[0]+x[4], t4=x[0]-x[4];
  f2 t1=x[1]+x[5], t5=x[1]-x[5];
  f2 t2=x[2]+x[6], t6=x[2]-x[6];
  f2 t3=x[3]+x[7], t7=x[3]-x[7];
  f2 b0=t0+t2, b2=t0-t2, b1=t1+t3, b3=t1-t3;
  f2 mb3 = mul_mi<INV>(b3);
  y[0]=b0+b1; y[4]=b0-b1; y[2]=b2+mb3; y[6]=b2-mb3;
  f2 v1 = mul_w81<INV>(t5), v2 = mul_mi<INV>(t6), v3 = mul_w83<INV>(t7);
  f2 a0=t4+v2, a2=t4-v2, a1=v1+v3, a3=v1-v3;
  f2 ma3 = mul_mi<INV>(a3);
  y[1]=a0+a1; y[5]=a0-a1; y[3]=a2+ma3; y[7]=a2-ma3;
}

template<bool INV>
static __device__ __forceinline__ void calc_w8(const f2* __restrict__ tw, int j, f2* w)
{
  f2 w1 = tw[j];
  if (INV) w1.y = -w1.y;
  w[1]=w1; w[2]=cmul(w1,w1); w[3]=cmul(w[2],w1); w[4]=cmul(w[2],w[2]);
  w[5]=cmul(w[3],w[2]); w[6]=cmul(w[3],w[3]); w[7]=cmul(w[4],w[3]);
}

static __device__ __forceinline__ void twstore(f2* __restrict__ dst, const f2* y, const f2* w,
                                               int base, int S)
{
  dst[PSWZ(base)]     = y[0];
  dst[PSWZ(base+S)]   = cmul(y[1],w[1]);
  dst[PSWZ(base+2*S)] = cmul(y[2],w[2]);
  dst[PSWZ(base+3*S)] = cmul(y[3],w[3]);
  dst[PSWZ(base+4*S)] = cmul(y[4],w[4]);
  dst[PSWZ(base+5*S)] = cmul(y[5],w[5]);
  dst[PSWZ(base+6*S)] = cmul(y[6],w[6]);
  dst[PSWZ(base+7*S)] = cmul(y[7],w[7]);
}

template<bool INV>
static __device__ __forceinline__ void bfly8_store(f2* __restrict__ dst, const f2* __restrict__ tw,
                                                   f2* x, int j, int base, int S)
{
  f2 y[8]; bfly8<INV>(x, y);
  f2 w[8]; calc_w8<INV>(tw, j, w);
  twstore(dst, y, w, base, S);
}

template<bool INV, bool ZTOP>
static __device__ __forceinline__ void stage8_first(const f2* __restrict__ src, f2* __restrict__ dst,
                                                    const f2* __restrict__ tw, int t, int st)
{
  const f2* sp = src + st;
  f2 x[8];
  if (ZTOP) {
    #pragma unroll
    for (int q = 0; q < 4; ++q) { x[q] = sp[256*q]; x[q+4] = mkf2(0.f, 0.f); }
  } else {
    #pragma unroll
    for (int q = 0; q < 8; ++q) x[q] = sp[256*q];
  }
  bfly8_store<INV>(dst, tw, x, t, t*8, 1);
}

template<bool INV, int S>
static __device__ __forceinline__ void stage8_mid(const f2* __restrict__ src, f2* __restrict__ dst,
                                                  const f2* __restrict__ tw, int t, int st)
{
  const f2* sp = src + st;
  f2 x[8];
  #pragma unroll
  for (int q = 0; q < 8; ++q) x[q] = sp[256*q];
  int i = t & (S-1);
  int j = t - i;
  bfly8_store<INV>(dst, tw, x, j, i + j*8, S);
}

// In-place mid stage: read 8 -> barrier -> write 8 (Stockham bijection => safe).
template<bool INV, int S>
static __device__ __forceinline__ void stage8_mid_ip(f2* __restrict__ buf, const f2* __restrict__ tw,
                                                     int t, int st)
{
  f2 x[8];
  #pragma unroll
  for (int q = 0; q < 8; ++q) x[q] = buf[st + 256*q];
  __syncthreads();
  int i = t & (S-1);
  int j = t - i;
  bfly8_store<INV>(buf, tw, x, j, i + j*8, S);
  __syncthreads();
}

template<bool INV, bool HALFOUT>
static __device__ __forceinline__ void stage4f(const f2* __restrict__ src, f2* __restrict__ dst, int st)
{
  #pragma unroll
  for (int hh = 0; hh < 2; ++hh) {
    const f2* sp = src + st + 256*hh;
    f2* wp = dst + st + 256*hh;
    f2 x0=sp[0], x1=sp[512], x2=sp[1024], x3=sp[1536];
    f2 a0=x0+x2, a2=x0-x2, a1=x1+x3, a3=x1-x3;
    f2 m = mul_mi<INV>(a3);
    wp[0]   = a0+a1;
    wp[512] = a2+m;
    if (!HALFOUT) {
      wp[1024] = a0-a1;
      wp[1536] = a2-m;
    }
  }
}

// In-place full-output radix-4 final stage: read 8 -> barrier -> write 8.
template<bool INV>
static __device__ __forceinline__ void stage4f_ip(f2* __restrict__ buf, int st)
{
  f2 xr[2][4];
  #pragma unroll
  for (int hh = 0; hh < 2; ++hh) {
    const f2* sp = buf + st + 256*hh;
    xr[hh][0]=sp[0]; xr[hh][1]=sp[512]; xr[hh][2]=sp[1024]; xr[hh][3]=sp[1536];
  }
  __syncthreads();
  #pragma unroll
  for (int hh = 0; hh < 2; ++hh) {
    f2* wp = buf + st + 256*hh;
    f2 a0=xr[hh][0]+xr[hh][2], a2=xr[hh][0]-xr[hh][2];
    f2 a1=xr[hh][1]+xr[hh][3], a3=xr[hh][1]-xr[hh][3];
    f2 m = mul_mi<INV>(a3);
    wp[0]    = a0+a1;
    wp[512]  = a2+m;
    wp[1024] = a0-a1;
    wp[1536] = a2-m;
  }
  __syncthreads();
}

// stage4 to registers: out[q] = element t+256q  (q = hh + 2k)
template<bool INV>
static __device__ __forceinline__ void stage4f_reg(const f2* __restrict__ src, f2* out, int st)
{
  #pragma unroll
  for (int hh = 0; hh < 2; ++hh) {
    const f2* sp = src + st + 256*hh;
    f2 x0=sp[0], x1=sp[512], x2=sp[1024], x3=sp[1536];
    f2 a0=x0+x2, a2=x0-x2, a1=x1+x3, a3=x1-x3;
    f2 m = mul_mi<INV>(a3);
    out[hh]   = a0+a1;
    out[hh+2] = a2+m;
    out[hh+4] = a0-a1;
    out[hh+6] = a2-m;
  }
}

static __device__ __forceinline__ f2 init_tw(f2* tw, int t)
{
  float s, c;
  sincosf(-6.2831853071795864769f * (float)t / (float)FFTN, &s, &c);
  f2 v = mkf2(c, s);
  tw[t] = v;   // exponents used are 0..248
  return v;    // u = exp(-2*pi*i*t/2048)
}

// Launch 1: fat kernel — blocks [0,4096): (B,L,H)->(B,H,L) transpose; blocks [4096,4160): cden.
__global__ __launch_bounds__(256) void kprep(
    const float* __restrict__ r, float* __restrict__ rT,
    const float* __restrict__ B_re, const float* __restrict__ B_im,
    const float* __restrict__ P_re, const float* __restrict__ P_im,
    const float* __restrict__ Q_re, const float* __restrict__ Q_im,
    const float* __restrict__ diag_re, const float* __restrict__ diag_im,
    const float* __restrict__ step,
    f2* __restrict__ cdenT, f2* __restrict__ f2v, f2* __restrict__ facv)
{
  __shared__ float til[64][65];
  int bid = blockIdx.x;
  int t = threadIdx.x;
  if (bid < 4096) {
    int tx = t & 15, ty = t >> 4;
    int h0 = (bid & 15) * 64, l0 = ((bid >> 4) & 31) * 64, b = bid >> 9;
    const float4* s4 = (const float4*)(r + ((size_t)b*SSM_L + l0)*SSM_H + h0);
    #pragma unroll
    for (int i = 0; i < 4; ++i) {
      int lr = ty + 16*i;
      float4 v = s4[(size_t)lr*(SSM_H/4) + tx];
      til[lr][4*tx+0]=v.x; til[lr][4*tx+1]=v.y; til[lr][4*tx+2]=v.z; til[lr][4*tx+3]=v.w;
    }
    __syncthreads();
    float4* d4 = (float4*)(rT + ((size_t)b*SSM_H + h0)*SSM_L + l0);
    #pragma unroll
    for (int i = 0; i < 4; ++i) {
      int hr = ty + 16*i;
      float4 w;
      w.x = til[4*tx+0][hr]; w.y = til[4*tx+1][hr];
      w.z = til[4*tx+2][hr]; w.w = til[4*tx+3][hr];
      d4[(size_t)hr*(SSM_L/4) + tx] = w;
    }
  } else {
    int gid = (bid - 4096) * 256 + t;     // 16384 threads, 8 per l
    int l = gid >> 3, s = gid & 7;
    double stepc = (double)step[0]; if (stepc < 1e-6) stepc = 1e-6;
    double ang = -2.0 * 3.14159265358979323846 * (double)l / (double)SSM_L;
    double zr = cos(ang), zi = sin(ang);
    double dr = 1.0 + zr, di = zi;
    double nr = 1.0 - zr, ni = -zi;
    double den = dr*dr + di*di;
    double i2s = 2.0 / stepc;
    double gr = i2s * (nr*dr + ni*di) / den;
    double gi = i2s * (ni*dr - nr*di) / den;
    double k10r=0.0, k10i=0.0, k11r=0.0, k11i=0.0;
    #pragma unroll
    for (int q = 0; q < 8; ++q) {
      int n = s*8 + q;
      double ar = gr - (double)diag_re[n];
      double ai = gi - (double)diag_im[n];
      double d2 = ar*ar + ai*ai;
      double cr = ar/d2, ci = -ai/d2;
      cdenT[n*SSM_L + l] = mkf2((float)cr, (float)ci);
      double qr = (double)Q_re[n], qi = (double)Q_im[n];
      double br = (double)B_re[n], bi = (double)B_im[n];
      double pr = (double)P_re[n], pi = (double)P_im[n];
      double qbr = qr*br - qi*bi, qbi = qr*bi + qi*br;
      double qpr = qr*pr - qi*pi, qpi = qr*pi + qi*pr;
      k10r += qbr*cr - qbi*ci; k10i += qbr*ci + qbi*cr;
      k11r += qpr*cr - qpi*ci; k11i += qpr*ci + qpi*cr;
    }
    #pragma unroll
    for (int off = 1; off < 8; off <<= 1) {
      k10r += __shfl_xor(k10r, off);
      k10i += __shfl_xor(k10i, off);
      k11r += __shfl_xor(k11r, off);
      k11i += __shfl_xor(k11i, off);
    }
    if (s == 0) {
      f2v[l] = mkf2((float)(2.0*dr/den), (float)(-2.0*di/den));
      double er = 1.0 + k11r, ei = k11i;
      double ed = er*er + ei*ei;
      facv[l] = mkf2((float)((k10r*er + k10i*ei)/ed), (float)((k10i*er - k10r*ei)/ed));
    }
  }
}

// Launch 2: 512 threads/block (8 waves -> 16 waves/CU at 2 blocks/CU).
// Contraction: all 512 threads, 4 l-values each, both channels (shared cd loads).
// FFT phase: WAVE-SPLIT — threads 0-255 run channel 0's pipeline, 256-511 channel 1's.
// PQ coefficients: X[k] = P_k*C[k] + Q_k*conj(C[2048-k]),
//   P_k = (K_k(1-s) + conj(K_kk)(1+s))/4096,  Q_k = i*c*(K_k - conj(K_kk))/4096,
//   (s,c) = sincos(pi*k/2048), kk = 2048-k (K[2048] partners k=0).
__global__ __launch_bounds__(NT2, 4) void kkern(
    const float* __restrict__ C_re, const float* __restrict__ C_im,
    const float* __restrict__ B_re, const float* __restrict__ B_im,
    const float* __restrict__ P_re, const float* __restrict__ P_im,
    const f2* __restrict__ cdenT, const f2* __restrict__ f2v, const f2* __restrict__ facv,
    float4* __restrict__ PQg)
{
  __shared__ f2 bufA[2][FFTN];
  __shared__ f2 bufB[2][FFTN];
  __shared__ f2 tw[256];
  int t = threadIdx.x;
  int tt = t & 255, ch = t >> 8, stt = PSWZ(tt);
  int h0 = blockIdx.x * 2;
  if (t < 256) init_tw(tw, t);
  f2* cbs = bufA[0];   // alias: dead once at_roots writes begin
  if (t < 128) {
    int h = h0 + (t >> 6), n = t & 63;
    f2 cc = mkf2(C_re[h*SSM_N + n], C_im[h*SSM_N + n]);
    cbs[t]       = cmul(cc, mkf2(B_re[n], B_im[n]));
    cbs[128 + t] = cmul(cc, mkf2(P_re[n], P_im[n]));
  }
  __syncthreads();
  f2 k00[2][4], k01[2][4];
  #pragma unroll
  for (int h2 = 0; h2 < 2; ++h2)
    #pragma unroll
    for (int i = 0; i < 4; ++i) { k00[h2][i] = mkf2(0.f,0.f); k01[h2][i] = mkf2(0.f,0.f); }
  f2 cd[4];
  #pragma unroll
  for (int i = 0; i < 4; ++i) cd[i] = cdenT[t + i*NT2];
  for (int n = 0; n < SSM_N; ++n) {
    f2 cdn[4];
    #pragma unroll
    for (int i = 0; i < 4; ++i) cdn[i] = cdenT[((n+1)&63)*SSM_L + t + i*NT2];
    #pragma unroll
    for (int h2 = 0; h2 < 2; ++h2) {
      f2 cb = cbs[h2*64 + n], cp = cbs[128 + h2*64 + n];
      #pragma unroll
      for (int i = 0; i < 4; ++i) {
        k00[h2][i] = k00[h2][i] + cmul(cb, cd[i]);
        k01[h2][i] = k01[h2][i] + cmul(cp, cd[i]);
      }
    }
    #pragma unroll
    for (int i = 0; i < 4; ++i) cd[i] = cdn[i];
  }
  __syncthreads();                          // contraction's cbs readers done
  #pragma unroll
  for (int h2 = 0; h2 < 2; ++h2)
    #pragma unroll
    for (int i = 0; i < 4; ++i) {
      int l = t + i*NT2;
      f2 fv = f2v[l], fc = facv[l];
      bufA[h2][PSWZ(l)] = cmul(fv, k00[h2][i] - cmul(k01[h2][i], fc));
    }
  __syncthreads();
  // ---- channel-split FFT phase: this thread owns channel ch, index tt ----
  f2* A  = bufA[ch];
  f2* Bb = bufB[ch];
  f2 ebin[4], e2048 = mkf2(0.f, 0.f);
  #pragma unroll
  for (int i = 0; i < 4; ++i) {             // even bins of K-hat (Hermitian part) -> regs
    int m = tt + i*256;
    if (m == 0) {
      ebin[0] = mkf2(A[0].x, 0.f);
      e2048   = mkf2(A[PSWZ(FFTN/2)].x, 0.f);
    } else {
      ebin[i] = 0.5f * (A[PSWZ(m)] + cconj(A[PSWZ(FFTN - m)]));
    }
  }
  stage8_first<true, false>(A, Bb, tw, tt, stt);     // iFFT stage 1
  __syncthreads();
  stage8_mid<true, 8>(Bb, A, tw, tt, stt);
  __syncthreads();
  stage8_mid<true, 64>(A, Bb, tw, tt, stt);
  __syncthreads();
  {                                         // iFFT stage4 -> regs; twist; fwd stage1 -> A
    f2 kr[8];
    stage4f_reg<true>(Bb, kr, stt);
    float sbb, cbb;
    sincosf(-3.14159265358979f * (float)tt / (float)FFTN, &sbb, &cbb);
    f2 cbase = mkf2(cbb, sbb);              // exp(-i*pi*tt/2048)
    const float Wc8[8] = {W8C0,W8C1,W8C2,W8C3,W8C4,W8C5,W8C6,W8C7};
    const float Ws8[8] = {W8S0,W8S1,W8S2,W8S3,W8S4,W8S5,W8S6,W8S7};
    const float scale = 1.0f / (float)FFTN;
    #pragma unroll
    for (int q = 0; q < 8; ++q) {
      f2 tq = cmul(cbase, mkf2(Wc8[q], Ws8[q]));
      kr[q] = (kr[q].x * scale) * tq;
    }
    f2 w[8]; calc_w8<false>(tw, tt, w);
    f2 y[8]; bfly8<false>(kr, y); twstore(A, y, w, tt*8, 1);
  }
  __syncthreads();
  stage8_mid<false, 8>(A, Bb, tw, tt, stt);
  __syncthreads();
  stage8_mid<false, 64>(Bb, A, tw, tt, stt);
  __syncthreads();
  // fwd stage4 (half out) A -> B lower; stash even bins -> B upper (natural; slot 0 = K[2048])
  stage4f<false, true>(A, Bb, stt);
  #pragma unroll
  for (int i = 0; i < 4; ++i) {
    int m = tt + 256*i;
    f2 v = ebin[i];
    if (m == 0) v = e2048;
    Bb[1024 + m] = v;
  }
  __syncthreads();
  // PQ emission; trig via tw-products: even angle pi*m/1024 -> u*W8[2i];
  // odd angle pi*(2m+1)/2048 -> (c1*u)*W8[2i], c1 = exp(-i*pi/2048).
  f2 u = tw[tt];                            // exp(-i*pi*tt/1024)
  const float q4 = 1.0f / 4096.0f;          // 1/2 (Hermitian) * 1/2048 (iFFT scale)
  const f2 c1 = mkf2(0.99999882345170176f, -0.00153398018628477f);
  f2 base_odd = cmul(c1, u);
  const float Wc8[8] = {W8C0,W8C1,W8C2,W8C3,W8C4,W8C5,W8C6,W8C7};
  const float Ws8[8] = {W8S0,W8S1,W8S2,W8S3,W8S4,W8S5,W8S6,W8S7};
  float4* pqrow = PQg + (size_t)(h0 + ch) * FFTN;
  #pragma unroll
  for (int i = 0; i < 4; ++i) {
    int m = tt + 256*i;
    // even k = 2m: Ka = own ebin; Kb = K[2048-2m] from stash (slot 0 holds K[2048])
    f2 Ka = ebin[i];
    f2 Kb = Bb[1024 + ((1024 - m) & 1023)];
    f2 ee = cmul(u, mkf2(Wc8[2*i], Ws8[2*i]));
    float cv = ee.x, sv = -ee.y;
    float am = q4*(1.f - sv), ap = q4*(1.f + sv), cq = q4*cv;
    f2 P = mkf2(Ka.x*am + Kb.x*ap, Ka.y*am - Kb.y*ap);
    f2 dd = mkf2(Ka.x - Kb.x, Ka.y + Kb.y);               // Ka - conj(Kb)
    pqrow[2*m] = make_float4(P.x, P.y, -dd.y*cq, dd.x*cq);
    // odd k = 2m+1: from fwd-FFT half output (swizzled, lower half of B)
    f2 Ko = Bb[PSWZ(m)];
    f2 Kp = Bb[PSWZ(1023 - m)];
    f2 eo = cmul(base_odd, mkf2(Wc8[2*i], Ws8[2*i]));
    cv = eo.x; sv = -eo.y;
    am = q4*(1.f - sv); ap = q4*(1.f + sv); cq = q4*cv;
    f2 P2 = mkf2(Ko.x*am + Kp.x*ap, Ko.y*am - Kp.y*ap);
    f2 d2 = mkf2(Ko.x - Kp.x, Ko.y + Kp.y);
    pqrow[2*m+1] = make_float4(P2.x, P2.y, -d2.y*cq, d2.x*cq);
  }
}

// Launch 3: per (b,h) row in rT: rfft4096 (packed) -> X[k]=P*C[k]+Q*conj(C[kk]) -> irfft + D*r.
// SINGLE in-place LDS buffer (18 KB). __launch_bounds__(NT,6): 85-VGPR budget -> NO spill
// (round-3's (NT,8)=64-reg budget spilled to scratch: FETCH 49->164MB, WRITE 66->295MB).
// If allocator lands <=64 VGPR, HW still reaches the LDS-limited 8 blocks/CU.
// XCD-bijective block map keeps PQ-row sharers on one XCD.
__global__ __launch_bounds__(NT, 6) void kconv(float* __restrict__ rT,
                                               const float4* __restrict__ PQg,
                                               const float* __restrict__ Dp)
{
  __shared__ f2 buf[FFTN];
  __shared__ f2 tw[256];
  int t = threadIdx.x, st = PSWZ(t);
  int xc = blockIdx.x & 7, y = blockIdx.x >> 3;
  int h = xc * 128 + (y >> 3);
  int b = y & 7;
  float Dv = Dp[0];
  init_tw(tw, t);
  float* rrow = rT + ((size_t)b*SSM_H + h) * SSM_L;
  const f2* r2 = (const f2*)rrow;
  f2 rv[4];
  #pragma unroll
  for (int i = 0; i < 4; ++i) rv[i] = r2[t + i*NT];   // element t+256i (also D-term src)
  {                                                   // fwd stage 1 from regs, upper half zero
    f2 xx[8];
    #pragma unroll
    for (int q = 0; q < 4; ++q) { xx[q] = rv[q]; xx[q+4] = mkf2(0.f, 0.f); }
    bfly8_store<false>(buf, tw, xx, t, t*8, 1);       // buf cold: no prior readers
  }
  __syncthreads();
  stage8_mid_ip<false, 8>(buf, tw, t, st);
  stage8_mid_ip<false, 64>(buf, tw, t, st);
  const float4* pqrow = PQg + (size_t)h * FFTN;       // issue PQ loads; hidden under stage4
  float4 pq[8];
  #pragma unroll
  for (int i = 0; i < 8; ++i) pq[i] = pqrow[t + i*NT];
  stage4f_ip<false>(buf, st);                         // full spectrum in buf (swizzled natural)
  {                                                   // pointwise in regs -> inv stage 1
    f2 xx[8];
    #pragma unroll
    for (int i = 0; i < 8; ++i) {
      int k = t + i*NT;
      int kk = (FFTN - k) & (FFTN - 1);
      f2 Ck  = buf[st + i*NT];                        // PSWZ(t+256i) = st+256i
      f2 Ckk = buf[PSWZ(kk)];
      xx[i] = cmul(mkf2(pq[i].x, pq[i].y), Ck) + cmul(mkf2(pq[i].z, pq[i].w), cconj(Ckk));
    }
    __syncthreads();
    bfly8_store<true>(buf, tw, xx, t, t*8, 1);
  }
  __syncthreads();
  stage8_mid_ip<true, 8>(buf, tw, t, st);
  stage8_mid_ip<true, 64>(buf, tw, t, st);
  f2* o2 = (f2*)rrow;                                 // fused inv stage4 (half out) + writeback
  #pragma unroll
  for (int hh = 0; hh < 2; ++hh) {
    const f2* sp = buf + st + 256*hh;
    f2 x0=sp[0], x1=sp[512], x2=sp[1024], x3=sp[1536];
    f2 a0=x0+x2, a2=x0-x2, a1=x1+x3, a3=x1-x3;
    f2 mm = mul_mi<true>(a3);
    f2 y0 = a0+a1, y1 = a2+mm;                        // elements t+256hh, t+256hh+512 (1/N in PQ)
    f2 rA = rv[hh], rB = rv[hh+2];
    o2[t + 256*hh]       = mkf2(y0.x + Dv*rA.x, y0.y + Dv*rA.y);
    o2[t + 256*hh + 512] = mkf2(y1.x + Dv*rB.x, y1.y + Dv*rB.y);
  }
}

// Launch 4: (B,H,L) -> (B,L,H) transpose + exact GELU
__global__ __launch_bounds__(256) void ktback(const float* __restrict__ yT, float* __restrict__ out)
{
  __shared__ float til[64][65];
  int t = threadIdx.x, tx = t & 15, ty = t >> 4;
  int h0 = blockIdx.x * 64, l0 = blockIdx.y * 64, b = blockIdx.z;
  const float4* s4 = (const float4*)(yT + ((size_t)b*SSM_H + h0)*SSM_L + l0);
  #pragma unroll
  for (int i = 0; i < 4; ++i) {
    int hr = ty + 16*i;
    float4 v = s4[(size_t)hr*(SSM_L/4) + tx];
    til[hr][4*tx+0]=v.x; til[hr][4*tx+1]=v.y; til[hr][4*tx+2]=v.z; til[hr][4*tx+3]=v.w;
  }
  __syncthreads();
  float4* d4 = (float4*)(out + ((size_t)b*SSM_L + l0)*SSM_H + h0);
  #pragma unroll
  for (int i = 0; i < 4; ++i) {
    int lr = ty + 16*i;
    float4 w;
    float x0 = til[4*tx+0][lr], x1 = til[4*tx+1][lr];
    float x2 = til[4*tx+2][lr], x3 = til[4*tx+3][lr];
    w.x = 0.5f * x0 * (1.0f + erff(x0 * 0.70710678118654752f));
    w.y = 0.5f * x1 * (1.0f + erff(x1 * 0.70710678118654752f));
    w.z = 0.5f * x2 * (1.0f + erff(x2 * 0.70710678118654752f));
    w.w = 0.5f * x3 * (1.0f + erff(x3 * 0.70710678118654752f));
    d4[(size_t)lr*(SSM_H/4) + tx] = w;
  }
}

extern "C" void kernel_launch(void* const* d_in, const int* in_sizes, int n_in,
                              void* d_out, int out_size, void* d_ws, size_t ws_size,
                              hipStream_t stream)
{
  const float* r       = (const float*)d_in[0];
  const float* B_re    = (const float*)d_in[1];
  const float* B_im    = (const float*)d_in[2];
  const float* C_re    = (const float*)d_in[3];
  const float* C_im    = (const float*)d_in[4];
  const float* P_re    = (const float*)d_in[5];
  const float* P_im    = (const float*)d_in[6];
  const float* Q_re    = (const float*)d_in[7];
  const float* Q_im    = (const float*)d_in[8];
  const float* diag_re = (const float*)d_in[9];
  const float* diag_im = (const float*)d_in[10];
  const float* step    = (const float*)d_in[11];
  const float* Dp      = (const float*)d_in[12];
  float* out = (float*)d_out;

  char* p = (char*)d_ws;
  float* rT  = (float*)p;  p += (size_t)SSM_B*SSM_H*SSM_L*sizeof(float);   // 64 MiB
  f2* cdenT  = (f2*)p;     p += (size_t)SSM_N*SSM_L*sizeof(f2);            // 1 MiB
  f2* f2v    = (f2*)p;     p += (size_t)SSM_L*sizeof(f2);
  f2* facv   = (f2*)p;     p += (size_t)SSM_L*sizeof(f2);
  float4* PQ = (float4*)p; p += (size_t)SSM_H*FFTN*sizeof(float4);         // 32 MiB

  kprep<<<4096 + 64, 256, 0, stream>>>(r, rT, B_re, B_im, P_re, P_im, Q_re, Q_im,
                                       diag_re, diag_im, step, cdenT, f2v, facv);
  kkern<<<SSM_H/2, NT2, 0, stream>>>(C_re, C_im, B_re, B_im, P_re, P_im,
                                     cdenT, f2v, facv, PQ);
  kconv<<<SSM_B*SSM_H, NT, 0, stream>>>(rT, PQ, Dp);
  ktback<<<dim3(SSM_H/64, SSM_L/64, SSM_B), 256, 0, stream>>>(rT, out);
}

// Round 5
// 264.711 us; speedup vs baseline: 1.1688x; 1.0746x over previous
//
#include <hip/hip_runtime.h>
#include <math.h>

#define SSM_N 64
#define SSM_H 1024
#define SSM_L 2048
#define SSM_B 8
#define FFTN 2048
#define NT 256
#define NT2 512

// XOR swizzle on float2 index: touches bits 0-3 only, so PSWZ(a+256q)=PSWZ(a)+256q.
#define PSWZ(a) ((a) ^ (((a) >> 4) & 15))

typedef float f2 __attribute__((ext_vector_type(2)));
static __device__ __forceinline__ f2 mkf2(float a, float b){ f2 v; v.x = a; v.y = b; return v; }

static __device__ __forceinline__ f2 cmul(f2 a, f2 b){
  return mkf2(-a.y, a.y) * mkf2(b.y, b.x) + mkf2(a.x, a.x) * b;
}
static __device__ __forceinline__ f2 cconj(f2 a){ return mkf2(a.x, -a.y); }

template<bool INV> static __device__ __forceinline__ f2 mul_mi(f2 a){
  return INV ? mkf2(-a.y, a.x) : mkf2(a.y, -a.x);
}
template<bool INV> static __device__ __forceinline__ f2 mul_w81(f2 a){
  const float r = 0.70710678118654752440f;
  return INV ? (r * mkf2(a.x - a.y, a.y + a.x)) : (r * mkf2(a.x + a.y, a.y - a.x));
}
template<bool INV> static __device__ __forceinline__ f2 mul_w83(f2 a){
  const float r = 0.70710678118654752440f;
  return INV ? (r * mkf2(-(a.x + a.y), a.x - a.y)) : (r * mkf2(a.y - a.x, -(a.x + a.y)));
}

// exp(-i*pi*k/8) table (cos, -sin)
#define W8C0 1.f
#define W8S0 0.f
#define W8C1 0.92387953251f
#define W8S1 (-0.38268343236f)
#define W8C2 0.70710678119f
#define W8S2 (-0.70710678119f)
#define W8C3 0.38268343236f
#define W8S3 (-0.92387953251f)
#define W8C4 0.f
#define W8S4 (-1.f)
#define W8C5 (-0.38268343236f)
#define W8S5 (-0.92387953251f)
#define W8C6 (-0.70710678119f)
#define W8S6 (-0.70710678119f)
#define W8C7 (-0.92387953251f)
#define W8S7 (-0.38268343236f)

template<bool INV>
static __device__ __forceinline__ void bfly8(const f2* x, f2* y)
{
  f2 t0=x[0]+x[4], t4=x[0]-x[4];
  f2 t1=x[1]+x[5], t5=x[1]-x[5];
  f2 t2=x[2]+x[6], t6=x[2]-x[6];
  f2 t3=x[3]+x[7], t7=x[3]-x[7];
  f2 b0=t0+t2, b2=t0-t2, b1=t1+t3, b3=t1-t3;
  f2 mb3 = mul_mi<INV>(b3);
  y[0]=b0+b1; y[4]=b0-b1; y[2]=b2+mb3; y[6]=b2-mb3;
  f2 v1 = mul_w81<INV>(t5), v2 = mul_mi<INV>(t6), v3 = mul_w83<INV>(t7);
  f2 a0=t4+v2, a2=t4-v2, a1=v1+v3, a3=v1-v3;
  f2 ma3 = mul_mi<INV>(a3);
  y[1]=a0+a1; y[5]=a0-a1; y[3]=a2+ma3; y[7]=a2-ma3;
}

template<bool INV>
static __device__ __forceinline__ void calc_w8(const f2* __restrict__ tw, int j, f2* w)
{
  f2 w1 = tw[j];
  if (INV) w1.y = -w1.y;
  w[1]=w1; w[2]=cmul(w1,w1); w[3]=cmul(w[2],w1); w[4]=cmul(w[2],w[2]);
  w[5]=cmul(w[3],w[2]); w[6]=cmul(w[3],w[3]); w[7]=cmul(w[4],w[3]);
}

static __device__ __forceinline__ void twstore(f2* __restrict__ dst, const f2* y, const f2* w,
                                               int base, int S)
{
  dst[PSWZ(base)]     = y[0];
  dst[PSWZ(base+S)]   = cmul(y[1],w[1]);
  dst[PSWZ(base+2*S)] = cmul(y[2],w[2]);
  dst[PSWZ(base+3*S)] = cmul(y[3],w[3]);
  dst[PSWZ(base+4*S)] = cmul(y[4],w[4]);
  dst[PSWZ(base+5*S)] = cmul(y[5],w[5]);
  dst[PSWZ(base+6*S)] = cmul(y[6],w[6]);
  dst[PSWZ(base+7*S)] = cmul(y[7],w[7]);
}

template<bool INV>
static __device__ __forceinline__ void bfly8_store(f2* __restrict__ dst, const f2* __restrict__ tw,
                                                   f2* x, int j, int base, int S)
{
  f2 y[8]; bfly8<INV>(x, y);
  f2 w[8]; calc_w8<INV>(tw, j, w);
  twstore(dst, y, w, base, S);
}

template<bool INV, bool ZTOP>
static __device__ __forceinline__ void stage8_first(const f2* __restrict__ src, f2* __restrict__ dst,
                                                    const f2* __restrict__ tw, int t, int st)
{
  const f2* sp = src + st;
  f2 x[8];
  if (ZTOP) {
    #pragma unroll
    for (int q = 0; q < 4; ++q) { x[q] = sp[256*q]; x[q+4] = mkf2(0.f, 0.f); }
  } else {
    #pragma unroll
    for (int q = 0; q < 8; ++q) x[q] = sp[256*q];
  }
  bfly8_store<INV>(dst, tw, x, t, t*8, 1);
}

template<bool INV, int S>
static __device__ __forceinline__ void stage8_mid(const f2* __restrict__ src, f2* __restrict__ dst,
                                                  const f2* __restrict__ tw, int t, int st)
{
  const f2* sp = src + st;
  f2 x[8];
  #pragma unroll
  for (int q = 0; q < 8; ++q) x[q] = sp[256*q];
  int i = t & (S-1);
  int j = t - i;
  bfly8_store<INV>(dst, tw, x, j, i + j*8, S);
}

// In-place mid stage: read 8 -> barrier -> write 8 (Stockham bijection => safe).
template<bool INV, int S>
static __device__ __forceinline__ void stage8_mid_ip(f2* __restrict__ buf, const f2* __restrict__ tw,
                                                     int t, int st)
{
  f2 x[8];
  #pragma unroll
  for (int q = 0; q < 8; ++q) x[q] = buf[st + 256*q];
  __syncthreads();
  int i = t & (S-1);
  int j = t - i;
  bfly8_store<INV>(buf, tw, x, j, i + j*8, S);
  __syncthreads();
}

template<bool INV, bool HALFOUT>
static __device__ __forceinline__ void stage4f(const f2* __restrict__ src, f2* __restrict__ dst, int st)
{
  #pragma unroll
  for (int hh = 0; hh < 2; ++hh) {
    const f2* sp = src + st + 256*hh;
    f2* wp = dst + st + 256*hh;
    f2 x0=sp[0], x1=sp[512], x2=sp[1024], x3=sp[1536];
    f2 a0=x0+x2, a2=x0-x2, a1=x1+x3, a3=x1-x3;
    f2 m = mul_mi<INV>(a3);
    wp[0]   = a0+a1;
    wp[512] = a2+m;
    if (!HALFOUT) {
      wp[1024] = a0-a1;
      wp[1536] = a2-m;
    }
  }
}

// In-place full-output radix-4 final stage: read 8 -> barrier -> write 8.
template<bool INV>
static __device__ __forceinline__ void stage4f_ip(f2* __restrict__ buf, int st)
{
  f2 xr[2][4];
  #pragma unroll
  for (int hh = 0; hh < 2; ++hh) {
    const f2* sp = buf + st + 256*hh;
    xr[hh][0]=sp[0]; xr[hh][1]=sp[512]; xr[hh][2]=sp[1024]; xr[hh][3]=sp[1536];
  }
  __syncthreads();
  #pragma unroll
  for (int hh = 0; hh < 2; ++hh) {
    f2* wp = buf + st + 256*hh;
    f2 a0=xr[hh][0]+xr[hh][2], a2=xr[hh][0]-xr[hh][2];
    f2 a1=xr[hh][1]+xr[hh][3], a3=xr[hh][1]-xr[hh][3];
    f2 m = mul_mi<INV>(a3);
    wp[0]    = a0+a1;
    wp[512]  = a2+m;
    wp[1024] = a0-a1;
    wp[1536] = a2-m;
  }
  __syncthreads();
}

// stage4 to registers: out[q] = element t+256q  (q = hh + 2k)
template<bool INV>
static __device__ __forceinline__ void stage4f_reg(const f2* __restrict__ src, f2* out, int st)
{
  #pragma unroll
  for (int hh = 0; hh < 2; ++hh) {
    const f2* sp = src + st + 256*hh;
    f2 x0=sp[0], x1=sp[512], x2=sp[1024], x3=sp[1536];
    f2 a0=x0+x2, a2=x0-x2, a1=x1+x3, a3=x1-x3;
    f2 m = mul_mi<INV>(a3);
    out[hh]   = a0+a1;
    out[hh+2] = a2+m;
    out[hh+4] = a0-a1;
    out[hh+6] = a2-m;
  }
}

static __device__ __forceinline__ f2 init_tw(f2* tw, int t)
{
  float s, c;
  sincosf(-6.2831853071795864769f * (float)t / (float)FFTN, &s, &c);
  f2 v = mkf2(c, s);
  tw[t] = v;   // exponents used are 0..248
  return v;    // u = exp(-2*pi*i*t/2048)
}

// Launch 1: fat kernel — blocks [0,4096): (B,L,H)->(B,H,L) transpose; blocks [4096,4160): cden.
__global__ __launch_bounds__(256) void kprep(
    const float* __restrict__ r, float* __restrict__ rT,
    const float* __restrict__ B_re, const float* __restrict__ B_im,
    const float* __restrict__ P_re, const float* __restrict__ P_im,
    const float* __restrict__ Q_re, const float* __restrict__ Q_im,
    const float* __restrict__ diag_re, const float* __restrict__ diag_im,
    const float* __restrict__ step,
    f2* __restrict__ cdenT, f2* __restrict__ f2v, f2* __restrict__ facv)
{
  __shared__ float til[64][65];
  int bid = blockIdx.x;
  int t = threadIdx.x;
  if (bid < 4096) {
    int tx = t & 15, ty = t >> 4;
    int h0 = (bid & 15) * 64, l0 = ((bid >> 4) & 31) * 64, b = bid >> 9;
    const float4* s4 = (const float4*)(r + ((size_t)b*SSM_L + l0)*SSM_H + h0);
    #pragma unroll
    for (int i = 0; i < 4; ++i) {
      int lr = ty + 16*i;
      float4 v = s4[(size_t)lr*(SSM_H/4) + tx];
      til[lr][4*tx+0]=v.x; til[lr][4*tx+1]=v.y; til[lr][4*tx+2]=v.z; til[lr][4*tx+3]=v.w;
    }
    __syncthreads();
    float4* d4 = (float4*)(rT + ((size_t)b*SSM_H + h0)*SSM_L + l0);
    #pragma unroll
    for (int i = 0; i < 4; ++i) {
      int hr = ty + 16*i;
      float4 w;
      w.x = til[4*tx+0][hr]; w.y = til[4*tx+1][hr];
      w.z = til[4*tx+2][hr]; w.w = til[4*tx+3][hr];
      d4[(size_t)hr*(SSM_L/4) + tx] = w;
    }
  } else {
    int gid = (bid - 4096) * 256 + t;     // 16384 threads, 8 per l
    int l = gid >> 3, s = gid & 7;
    double stepc = (double)step[0]; if (stepc < 1e-6) stepc = 1e-6;
    double ang = -2.0 * 3.14159265358979323846 * (double)l / (double)SSM_L;
    double zr = cos(ang), zi = sin(ang);
    double dr = 1.0 + zr, di = zi;
    double nr = 1.0 - zr, ni = -zi;
    double den = dr*dr + di*di;
    double i2s = 2.0 / stepc;
    double gr = i2s * (nr*dr + ni*di) / den;
    double gi = i2s * (ni*dr - nr*di) / den;
    double k10r=0.0, k10i=0.0, k11r=0.0, k11i=0.0;
    #pragma unroll
    for (int q = 0; q < 8; ++q) {
      int n = s*8 + q;
      double ar = gr - (double)diag_re[n];
      double ai = gi - (double)diag_im[n];
      double d2 = ar*ar + ai*ai;
      double cr = ar/d2, ci = -ai/d2;
      cdenT[n*SSM_L + l] = mkf2((float)cr, (float)ci);
      double qr = (double)Q_re[n], qi = (double)Q_im[n];
      double br = (double)B_re[n], bi = (double)B_im[n];
      double pr = (double)P_re[n], pi = (double)P_im[n];
      double qbr = qr*br - qi*bi, qbi = qr*bi + qi*br;
      double qpr = qr*pr - qi*pi, qpi = qr*pi + qi*pr;
      k10r += qbr*cr - qbi*ci; k10i += qbr*ci + qbi*cr;
      k11r += qpr*cr - qpi*ci; k11i += qpr*ci + qpi*cr;
    }
    #pragma unroll
    for (int off = 1; off < 8; off <<= 1) {
      k10r += __shfl_xor(k10r, off);
      k10i += __shfl_xor(k10i, off);
      k11r += __shfl_xor(k11r, off);
      k11i += __shfl_xor(k11i, off);
    }
    if (s == 0) {
      f2v[l] = mkf2((float)(2.0*dr/den), (float)(-2.0*di/den));
      double er = 1.0 + k11r, ei = k11i;
      double ed = er*er + ei*ei;
      facv[l] = mkf2((float)((k10r*er + k10i*ei)/ed), (float)((k10i*er - k10r*ei)/ed));
    }
  }
}

// Launch 2: 512 threads/block (8 waves -> 16 waves/CU at 2 blocks/CU).
// Contraction: all 512 threads, 4 l-values each, both channels (shared cd loads).
// FFT phase: WAVE-SPLIT — threads 0-255 run channel 0's pipeline, 256-511 channel 1's.
// PQ coefficients: X[k] = P_k*C[k] + Q_k*conj(C[2048-k]),
//   P_k = (K_k(1-s) + conj(K_kk)(1+s))/4096,  Q_k = i*c*(K_k - conj(K_kk))/4096,
//   (s,c) = sincos(pi*k/2048), kk = 2048-k (K[2048] partners k=0).
__global__ __launch_bounds__(NT2, 4) void kkern(
    const float* __restrict__ C_re, const float* __restrict__ C_im,
    const float* __restrict__ B_re, const float* __restrict__ B_im,
    const float* __restrict__ P_re, const float* __restrict__ P_im,
    const f2* __restrict__ cdenT, const f2* __restrict__ f2v, const f2* __restrict__ facv,
    float4* __restrict__ PQg)
{
  __shared__ f2 bufA[2][FFTN];
  __shared__ f2 bufB[2][FFTN];
  __shared__ f2 tw[256];
  int t = threadIdx.x;
  int tt = t & 255, ch = t >> 8, stt = PSWZ(tt);
  int h0 = blockIdx.x * 2;
  if (t < 256) init_tw(tw, t);
  f2* cbs = bufA[0];   // alias: dead once at_roots writes begin
  if (t < 128) {
    int h = h0 + (t >> 6), n = t & 63;
    f2 cc = mkf2(C_re[h*SSM_N + n], C_im[h*SSM_N + n]);
    cbs[t]       = cmul(cc, mkf2(B_re[n], B_im[n]));
    cbs[128 + t] = cmul(cc, mkf2(P_re[n], P_im[n]));
  }
  __syncthreads();
  f2 k00[2][4], k01[2][4];
  #pragma unroll
  for (int h2 = 0; h2 < 2; ++h2)
    #pragma unroll
    for (int i = 0; i < 4; ++i) { k00[h2][i] = mkf2(0.f,0.f); k01[h2][i] = mkf2(0.f,0.f); }
  f2 cd[4];
  #pragma unroll
  for (int i = 0; i < 4; ++i) cd[i] = cdenT[t + i*NT2];
  for (int n = 0; n < SSM_N; ++n) {
    f2 cdn[4];
    #pragma unroll
    for (int i = 0; i < 4; ++i) cdn[i] = cdenT[((n+1)&63)*SSM_L + t + i*NT2];
    #pragma unroll
    for (int h2 = 0; h2 < 2; ++h2) {
      f2 cb = cbs[h2*64 + n], cp = cbs[128 + h2*64 + n];
      #pragma unroll
      for (int i = 0; i < 4; ++i) {
        k00[h2][i] = k00[h2][i] + cmul(cb, cd[i]);
        k01[h2][i] = k01[h2][i] + cmul(cp, cd[i]);
      }
    }
    #pragma unroll
    for (int i = 0; i < 4; ++i) cd[i] = cdn[i];
  }
  __syncthreads();                          // contraction's cbs readers done
  #pragma unroll
  for (int h2 = 0; h2 < 2; ++h2)
    #pragma unroll
    for (int i = 0; i < 4; ++i) {
      int l = t + i*NT2;
      f2 fv = f2v[l], fc = facv[l];
      bufA[h2][PSWZ(l)] = cmul(fv, k00[h2][i] - cmul(k01[h2][i], fc));
    }
  __syncthreads();
  // ---- channel-split FFT phase: this thread owns channel ch, index tt ----
  f2* A  = bufA[ch];
  f2* Bb = bufB[ch];
  f2 ebin[4], e2048 = mkf2(0.f, 0.f);
  #pragma unroll
  for (int i = 0; i < 4; ++i) {             // even bins of K-hat (Hermitian part) -> regs
    int m = tt + i*256;
    if (m == 0) {
      ebin[0] = mkf2(A[0].x, 0.f);
      e2048   = mkf2(A[PSWZ(FFTN/2)].x, 0.f);
    } else {
      ebin[i] = 0.5f * (A[PSWZ(m)] + cconj(A[PSWZ(FFTN - m)]));
    }
  }
  stage8_first<true, false>(A, Bb, tw, tt, stt);     // iFFT stage 1
  __syncthreads();
  stage8_mid<true, 8>(Bb, A, tw, tt, stt);
  __syncthreads();
  stage8_mid<true, 64>(A, Bb, tw, tt, stt);
  __syncthreads();
  {                                         // iFFT stage4 -> regs; twist; fwd stage1 -> A
    f2 kr[8];
    stage4f_reg<true>(Bb, kr, stt);
    float sbb, cbb;
    sincosf(-3.14159265358979f * (float)tt / (float)FFTN, &sbb, &cbb);
    f2 cbase = mkf2(cbb, sbb);              // exp(-i*pi*tt/2048)
    const float Wc8[8] = {W8C0,W8C1,W8C2,W8C3,W8C4,W8C5,W8C6,W8C7};
    const float Ws8[8] = {W8S0,W8S1,W8S2,W8S3,W8S4,W8S5,W8S6,W8S7};
    const float scale = 1.0f / (float)FFTN;
    #pragma unroll
    for (int q = 0; q < 8; ++q) {
      f2 tq = cmul(cbase, mkf2(Wc8[q], Ws8[q]));
      kr[q] = (kr[q].x * scale) * tq;
    }
    f2 w[8]; calc_w8<false>(tw, tt, w);
    f2 y[8]; bfly8<false>(kr, y); twstore(A, y, w, tt*8, 1);
  }
  __syncthreads();
  stage8_mid<false, 8>(A, Bb, tw, tt, stt);
  __syncthreads();
  stage8_mid<false, 64>(Bb, A, tw, tt, stt);
  __syncthreads();
  // fwd stage4 (half out) A -> B lower; stash even bins -> B upper (natural; slot 0 = K[2048])
  stage4f<false, true>(A, Bb, stt);
  #pragma unroll
  for (int i = 0; i < 4; ++i) {
    int m = tt + 256*i;
    f2 v = ebin[i];
    if (m == 0) v = e2048;
    Bb[1024 + m] = v;
  }
  __syncthreads();
  // PQ emission; trig via tw-products: even angle pi*m/1024 -> u*W8[2i];
  // odd angle pi*(2m+1)/2048 -> (c1*u)*W8[2i], c1 = exp(-i*pi/2048).
  f2 u = tw[tt];                            // exp(-i*pi*tt/1024)
  const float q4 = 1.0f / 4096.0f;          // 1/2 (Hermitian) * 1/2048 (iFFT scale)
  const f2 c1 = mkf2(0.99999882345170176f, -0.00153398018628477f);
  f2 base_odd = cmul(c1, u);
  const float Wc8[8] = {W8C0,W8C1,W8C2,W8C3,W8C4,W8C5,W8C6,W8C7};
  const float Ws8[8] = {W8S0,W8S1,W8S2,W8S3,W8S4,W8S5,W8S6,W8S7};
  float4* pqrow = PQg + (size_t)(h0 + ch) * FFTN;
  #pragma unroll
  for (int i = 0; i < 4; ++i) {
    int m = tt + 256*i;
    // even k = 2m: Ka = own ebin; Kb = K[2048-2m] from stash (slot 0 holds K[2048])
    f2 Ka = ebin[i];
    f2 Kb = Bb[1024 + ((1024 - m) & 1023)];
    f2 ee = cmul(u, mkf2(Wc8[2*i], Ws8[2*i]));
    float cv = ee.x, sv = -ee.y;
    float am = q4*(1.f - sv), ap = q4*(1.f + sv), cq = q4*cv;
    f2 P = mkf2(Ka.x*am + Kb.x*ap, Ka.y*am - Kb.y*ap);
    f2 dd = mkf2(Ka.x - Kb.x, Ka.y + Kb.y);               // Ka - conj(Kb)
    pqrow[2*m] = make_float4(P.x, P.y, -dd.y*cq, dd.x*cq);
    // odd k = 2m+1: from fwd-FFT half output (swizzled, lower half of B)
    f2 Ko = Bb[PSWZ(m)];
    f2 Kp = Bb[PSWZ(1023 - m)];
    f2 eo = cmul(base_odd, mkf2(Wc8[2*i], Ws8[2*i]));
    cv = eo.x; sv = -eo.y;
    am = q4*(1.f - sv); ap = q4*(1.f + sv); cq = q4*cv;
    f2 P2 = mkf2(Ko.x*am + Kp.x*ap, Ko.y*am - Kp.y*ap);
    f2 d2 = mkf2(Ko.x - Kp.x, Ko.y + Kp.y);
    pqrow[2*m+1] = make_float4(P2.x, P2.y, -d2.y*cq, d2.x*cq);
  }
}

// Launch 3: per (b,h) row in rT: rfft4096 (packed) -> X[k]=P*C[k]+Q*conj(C[kk]) -> irfft + D*r.
// SINGLE in-place LDS buffer (18 KB) -> 8 blocks/CU possible. __launch_bounds__(NT,4):
// empirically the backend's arch-VGPR cap behaves as ~256/min_waves (r3: min=8 -> 32 regs,
// r4: min=6 -> 40 regs, both SPILLED; min=4 -> 64-reg cap fits the ~60-reg live set, r0-r2
// compiled clean at 52). HW occupancy then comes from ACTUAL VGPR use (<=64 -> 8 waves/SIMD),
// not the launch-bounds floor. XCD-bijective block map keeps PQ-row sharers on one XCD.
__global__ __launch_bounds__(NT, 4) void kconv(float* __restrict__ rT,
                                               const float4* __restrict__ PQg,
                                               const float* __restrict__ Dp)
{
  __shared__ f2 buf[FFTN];
  __shared__ f2 tw[256];
  int t = threadIdx.x, st = PSWZ(t);
  int xc = blockIdx.x & 7, y = blockIdx.x >> 3;
  int h = xc * 128 + (y >> 3);
  int b = y & 7;
  float Dv = Dp[0];
  init_tw(tw, t);
  float* rrow = rT + ((size_t)b*SSM_H + h) * SSM_L;
  const f2* r2 = (const f2*)rrow;
  f2 rv[4];
  #pragma unroll
  for (int i = 0; i < 4; ++i) rv[i] = r2[t + i*NT];   // element t+256i (also D-term src)
  {                                                   // fwd stage 1 from regs, upper half zero
    f2 xx[8];
    #pragma unroll
    for (int q = 0; q < 4; ++q) { xx[q] = rv[q]; xx[q+4] = mkf2(0.f, 0.f); }
    bfly8_store<false>(buf, tw, xx, t, t*8, 1);       // buf cold: no prior readers
  }
  __syncthreads();
  stage8_mid_ip<false, 8>(buf, tw, t, st);
  stage8_mid_ip<false, 64>(buf, tw, t, st);
  const float4* pqrow = PQg + (size_t)h * FFTN;       // issue PQ loads; hidden under stage4
  float4 pq[8];
  #pragma unroll
  for (int i = 0; i < 8; ++i) pq[i] = pqrow[t + i*NT];
  stage4f_ip<false>(buf, st);                         // full spectrum in buf (swizzled natural)
  {                                                   // pointwise in regs -> inv stage 1
    f2 xx[8];
    #pragma unroll
    for (int i = 0; i < 8; ++i) {
      int k = t + i*NT;
      int kk = (FFTN - k) & (FFTN - 1);
      f2 Ck  = buf[st + i*NT];                        // PSWZ(t+256i) = st+256i
      f2 Ckk = buf[PSWZ(kk)];
      xx[i] = cmul(mkf2(pq[i].x, pq[i].y), Ck) + cmul(mkf2(pq[i].z, pq[i].w), cconj(Ckk));
    }
    __syncthreads();
    bfly8_store<true>(buf, tw, xx, t, t*8, 1);
  }
  __syncthreads();
  stage8_mid_ip<true, 8>(buf, tw, t, st);
  stage8_mid_ip<true, 64>(buf, tw, t, st);
  f2* o2 = (f2*)rrow;                                 // fused inv stage4 (half out) + writeback
  #pragma unroll
  for (int hh = 0; hh < 2; ++hh) {
    const f2* sp = buf + st + 256*hh;
    f2 x0=sp[0], x1=sp[512], x2=sp[1024], x3=sp[1536];
    f2 a0=x0+x2, a2=x0-x2, a1=x1+x3, a3=x1-x3;
    f2 mm = mul_mi<true>(a3);
    f2 y0 = a0+a1, y1 = a2+mm;                        // elements t+256hh, t+256hh+512 (1/N in PQ)
    f2 rA = rv[hh], rB = rv[hh+2];
    o2[t + 256*hh]       = mkf2(y0.x + Dv*rA.x, y0.y + Dv*rA.y);
    o2[t + 256*hh + 512] = mkf2(y1.x + Dv*rB.x, y1.y + Dv*rB.y);
  }
}

// Launch 4: (B,H,L) -> (B,L,H) transpose + exact GELU
__global__ __launch_bounds__(256) void ktback(const float* __restrict__ yT, float* __restrict__ out)
{
  __shared__ float til[64][65];
  int t = threadIdx.x, tx = t & 15, ty = t >> 4;
  int h0 = blockIdx.x * 64, l0 = blockIdx.y * 64, b = blockIdx.z;
  const float4* s4 = (const float4*)(yT + ((size_t)b*SSM_H + h0)*SSM_L + l0);
  #pragma unroll
  for (int i = 0; i < 4; ++i) {
    int hr = ty + 16*i;
    float4 v = s4[(size_t)hr*(SSM_L/4) + tx];
    til[hr][4*tx+0]=v.x; til[hr][4*tx+1]=v.y; til[hr][4*tx+2]=v.z; til[hr][4*tx+3]=v.w;
  }
  __syncthreads();
  float4* d4 = (float4*)(out + ((size_t)b*SSM_L + l0)*SSM_H + h0);
  #pragma unroll
  for (int i = 0; i < 4; ++i) {
    int lr = ty + 16*i;
    float4 w;
    float x0 = til[4*tx+0][lr], x1 = til[4*tx+1][lr];
    float x2 = til[4*tx+2][lr], x3 = til[4*tx+3][lr];
    w.x = 0.5f * x0 * (1.0f + erff(x0 * 0.70710678118654752f));
    w.y = 0.5f * x1 * (1.0f + erff(x1 * 0.70710678118654752f));
    w.z = 0.5f * x2 * (1.0f + erff(x2 * 0.70710678118654752f));
    w.w = 0.5f * x3 * (1.0f + erff(x3 * 0.70710678118654752f));
    d4[(size_t)lr*(SSM_H/4) + tx] = w;
  }
}

extern "C" void kernel_launch(void* const* d_in, const int* in_sizes, int n_in,
                              void* d_out, int out_size, void* d_ws, size_t ws_size,
                              hipStream_t stream)
{
  const float* r       = (const float*)d_in[0];
  const float* B_re    = (const float*)d_in[1];
  const float* B_im    = (const float*)d_in[2];
  const float* C_re    = (const float*)d_in[3];
  const float* C_im    = (const float*)d_in[4];
  const float* P_re    = (const float*)d_in[5];
  const float* P_im    = (const float*)d_in[6];
  const float* Q_re    = (const float*)d_in[7];
  const float* Q_im    = (const float*)d_in[8];
  const float* diag_re = (const float*)d_in[9];
  const float* diag_im = (const float*)d_in[10];
  const float* step    = (const float*)d_in[11];
  const float* Dp      = (const float*)d_in[12];
  float* out = (float*)d_out;

  char* p = (char*)d_ws;
  float* rT  = (float*)p;  p += (size_t)SSM_B*SSM_H*SSM_L*sizeof(float);   // 64 MiB
  f2* cdenT  = (f2*)p;     p += (size_t)SSM_N*SSM_L*sizeof(f2);            // 1 MiB
  f2* f2v    = (f2*)p;     p += (size_t)SSM_L*sizeof(f2);
  f2* facv   = (f2*)p;     p += (size_t)SSM_L*sizeof(f2);
  float4* PQ = (float4*)p; p += (size_t)SSM_H*FFTN*sizeof(float4);         // 32 MiB

  kprep<<<4096 + 64, 256, 0, stream>>>(r, rT, B_re, B_im, P_re, P_im, Q_re, Q_im,
                                       diag_re, diag_im, step, cdenT, f2v, facv);
  kkern<<<SSM_H/2, NT2, 0, stream>>>(C_re, C_im, B_re, B_im, P_re, P_im,
                                     cdenT, f2v, facv, PQ);
  kconv<<<SSM_B*SSM_H, NT, 0, stream>>>(rT, PQ, Dp);
  ktback<<<dim3(SSM_H/64, SSM_L/64, SSM_B), 256, 0, stream>>>(rT, out);
}